// Round 1
// baseline (272.471 us; speedup 1.0000x reference)
//
#include <hip/hip_runtime.h>

// RetrievalLoss: out[i] = -sum_k Q[i,k] * D[i,k]   (N=131072, D=256, fp32)
// Memory-bound: 269 MB traffic -> ~43 us floor at 6.3 TB/s.
//
// One wave (64 lanes) per row: each lane loads a float4 from Q and D
// (64 lanes x 16 B = 1024 B = exactly one row -> perfectly coalesced),
// partial dot in-lane, 6-step __shfl_xor butterfly across the wave,
// lane 0 stores -sum. Grid-stride over rows.

constexpr int kN = 131072;
constexpr int kD = 256;

__global__ __launch_bounds__(256) void neg_rowdot_kernel(
    const float* __restrict__ q, const float* __restrict__ d,
    float* __restrict__ out, int n_rows) {
  const int gwave = (blockIdx.x * blockDim.x + threadIdx.x) >> 6;  // global wave id
  const int lane = threadIdx.x & 63;
  const int nwaves = (gridDim.x * blockDim.x) >> 6;

  for (int row = gwave; row < n_rows; row += nwaves) {
    const float4* qr = reinterpret_cast<const float4*>(q + (size_t)row * kD);
    const float4* dr = reinterpret_cast<const float4*>(d + (size_t)row * kD);
    const float4 a = qr[lane];
    const float4 b = dr[lane];
    float s = a.x * b.x + a.y * b.y + a.z * b.z + a.w * b.w;
#pragma unroll
    for (int off = 32; off; off >>= 1) s += __shfl_xor(s, off, 64);
    if (lane == 0) out[row] = -s;
  }
}

extern "C" void kernel_launch(void* const* d_in, const int* in_sizes, int n_in,
                              void* d_out, int out_size, void* d_ws, size_t ws_size,
                              hipStream_t stream) {
  const float* q = reinterpret_cast<const float*>(d_in[0]);
  const float* d = reinterpret_cast<const float*>(d_in[1]);
  float* out = reinterpret_cast<float*>(d_out);

  // 2048 blocks x 256 threads = 8192 waves (32 waves/CU across 256 CUs);
  // each wave grid-strides over 131072/8192 = 16 rows.
  neg_rowdot_kernel<<<2048, 256, 0, stream>>>(q, d, out, kN);
}